// Round 2
// baseline (219.713 us; speedup 1.0000x reference)
//
#include <hip/hip_runtime.h>
#include <math.h>

#define N_NODES 1024
#define IN_F 512
#define N_HEADS 4
#define N_HID 32
#define OUT_F 128   // N_HEADS*N_HID
#define NEG_SLOPE 0.2f

// ---------------- Kernel A: g_l = h@W_l, g_r = h@W_r (fused cols) ----------
// 256 blocks x 256 threads. Block = 4 h-rows; lane = fused col (0-127 Wl,
// 128-255 Wr). h-row loads are wave-uniform (broadcast/s_load); W streamed
// coalesced (1KB per k across the block). Also zero-inits den[4][1024].
__global__ __launch_bounds__(256) void gat_gemm(
    const float* __restrict__ hmat, const float* __restrict__ Wl,
    const float* __restrict__ Wr, float* __restrict__ gl,
    float* __restrict__ gr, float* __restrict__ den)
{
  if (blockIdx.x < 16) den[blockIdx.x * 256 + threadIdx.x] = 0.f;

  const int r0 = blockIdx.x * 4;
  const int c = threadIdx.x;
  const float* __restrict__ W = (c < 128) ? Wl : Wr;
  float* __restrict__ outp = (c < 128) ? gl : gr;
  const int cc = c & 127;

  float acc0 = 0.f, acc1 = 0.f, acc2 = 0.f, acc3 = 0.f;
#pragma unroll 2
  for (int k = 0; k < IN_F; k += 8) {
    float4 ha0 = *(const float4*)(hmat + (size_t)(r0 + 0) * IN_F + k);
    float4 ha1 = *(const float4*)(hmat + (size_t)(r0 + 0) * IN_F + k + 4);
    float4 hb0 = *(const float4*)(hmat + (size_t)(r0 + 1) * IN_F + k);
    float4 hb1 = *(const float4*)(hmat + (size_t)(r0 + 1) * IN_F + k + 4);
    float4 hc0 = *(const float4*)(hmat + (size_t)(r0 + 2) * IN_F + k);
    float4 hc1 = *(const float4*)(hmat + (size_t)(r0 + 2) * IN_F + k + 4);
    float4 hd0 = *(const float4*)(hmat + (size_t)(r0 + 3) * IN_F + k);
    float4 hd1 = *(const float4*)(hmat + (size_t)(r0 + 3) * IN_F + k + 4);
    float w[8];
#pragma unroll
    for (int kk = 0; kk < 8; ++kk) w[kk] = W[(size_t)(k + kk) * OUT_F + cc];
    const float* pa0 = &ha0.x; const float* pa1 = &ha1.x;
    const float* pb0 = &hb0.x; const float* pb1 = &hb1.x;
    const float* pc0 = &hc0.x; const float* pc1 = &hc1.x;
    const float* pd0 = &hd0.x; const float* pd1 = &hd1.x;
#pragma unroll
    for (int kk = 0; kk < 4; ++kk) {
      acc0 = fmaf(pa0[kk], w[kk], acc0);
      acc1 = fmaf(pb0[kk], w[kk], acc1);
      acc2 = fmaf(pc0[kk], w[kk], acc2);
      acc3 = fmaf(pd0[kk], w[kk], acc3);
    }
#pragma unroll
    for (int kk = 0; kk < 4; ++kk) {
      acc0 = fmaf(pa1[kk], w[kk + 4], acc0);
      acc1 = fmaf(pb1[kk], w[kk + 4], acc1);
      acc2 = fmaf(pc1[kk], w[kk + 4], acc2);
      acc3 = fmaf(pd1[kk], w[kk + 4], acc3);
    }
  }
  outp[(size_t)(r0 + 0) * OUT_F + cc] = acc0;
  outp[(size_t)(r0 + 1) * OUT_F + cc] = acc1;
  outp[(size_t)(r0 + 2) * OUT_F + cc] = acc2;
  outp[(size_t)(r0 + 3) * OUT_F + cc] = acc3;
}

// ---------------- Kernel B: p^T[h][j][i] = adj ? exp(e) : 0; den += sums ---
// grid (128 i-tiles, 32 j-tiles), 256 threads.
// thread: jl = tid&31 (its j), hh = (tid>>5)&3, is = tid>>7; owns 4 i's
// (i0 + is*4 + 0..3) with g_r in registers. g_l j-tile staged in LDS
// (float4 stride 33 -> conflict-free b128). No max-subtraction (|e| <~ 11).
__global__ __launch_bounds__(256) void gat_escore(
    const float* __restrict__ gl, const float* __restrict__ gr,
    const float* __restrict__ attn_w, const int* __restrict__ adj,
    float* __restrict__ p, float* __restrict__ den)
{
  __shared__ float4 gls[32][33];  // [j][f4 global 0..31], pad to 33
  const int i0 = blockIdx.x * 8;
  const int jb = blockIdx.y * 32;
  {
    const int row = threadIdx.x >> 3;
    const int f4b = threadIdx.x & 7;
#pragma unroll
    for (int q = 0; q < 4; ++q) {
      const int f4 = f4b + 8 * q;
      gls[row][f4] = *(const float4*)(gl + (size_t)(jb + row) * OUT_F + f4 * 4);
    }
  }
  const int jl = threadIdx.x & 31;
  const int hh = (threadIdx.x >> 5) & 3;
  const int is = threadIdx.x >> 7;
  const int ibase = i0 + is * 4;

  // g_r for 4 i's, this head: 4 x 8 float4 in registers (static indexing!)
  float4 gg[4][8];
#pragma unroll
  for (int ii = 0; ii < 4; ++ii)
#pragma unroll
    for (int f4 = 0; f4 < 8; ++f4)
      gg[ii][f4] =
          *(const float4*)(gr + (size_t)(ibase + ii) * OUT_F + hh * N_HID + f4 * 4);

  float aw[N_HID];
#pragma unroll
  for (int f = 0; f < N_HID; ++f) aw[f] = attn_w[f];
  __syncthreads();

  float acc[4] = {0.f, 0.f, 0.f, 0.f};
#pragma unroll
  for (int f4 = 0; f4 < 8; ++f4) {
    const float4 gv = gls[jl][hh * 8 + f4];
    const float g0 = gv.x, g1 = gv.y, g2 = gv.z, g3 = gv.w;
#pragma unroll
    for (int ii = 0; ii < 4; ++ii) {
      float s;
      s = g0 + gg[ii][f4].x;
      acc[ii] = fmaf(fmaxf(s, NEG_SLOPE * s), aw[f4 * 4 + 0], acc[ii]);
      s = g1 + gg[ii][f4].y;
      acc[ii] = fmaf(fmaxf(s, NEG_SLOPE * s), aw[f4 * 4 + 1], acc[ii]);
      s = g2 + gg[ii][f4].z;
      acc[ii] = fmaf(fmaxf(s, NEG_SLOPE * s), aw[f4 * 4 + 2], acc[ii]);
      s = g3 + gg[ii][f4].w;
      acc[ii] = fmaf(fmaxf(s, NEG_SLOPE * s), aw[f4 * 4 + 3], acc[ii]);
    }
  }

  const int j = jb + jl;
  float4 pv;
  float* pvp = &pv.x;
#pragma unroll
  for (int ii = 0; ii < 4; ++ii) {
    const int a = adj[(size_t)(ibase + ii) * N_NODES + j];
    pvp[ii] = a ? __expf(acc[ii]) : 0.f;
  }
  *(float4*)(p + ((size_t)hh * N_NODES + j) * N_NODES + ibase) = pv;

  // den[h][i] += sum over jl of p: butterfly over jl bits (1..16), then
  // lane jl==0 of each (hh,is) group atomics 4 values.
  float d0 = pv.x, d1 = pv.y, d2 = pv.z, d3 = pv.w;
#pragma unroll
  for (int m = 1; m < 32; m <<= 1) {
    d0 += __shfl_xor(d0, m);
    d1 += __shfl_xor(d1, m);
    d2 += __shfl_xor(d2, m);
    d3 += __shfl_xor(d3, m);
  }
  if (jl == 0) {
    atomicAdd(&den[hh * N_NODES + ibase + 0], d0);
    atomicAdd(&den[hh * N_NODES + ibase + 1], d1);
    atomicAdd(&den[hh * N_NODES + ibase + 2], d2);
    atomicAdd(&den[hh * N_NODES + ibase + 3], d3);
  }
}

// ---------------- Kernel C: out[i][h*32+f] = ELU( (sum_j p^T[h][j][i] *
// gr[j][h*32+f]) / den[h][i] ). grid 256 blocks (64 i-tiles x 4 heads),
// 256 threads = (f 32, ig 8), 2 i's per thread (float2 p loads).
__global__ __launch_bounds__(256) void gat_aggr(
    const float* __restrict__ p, const float* __restrict__ gr,
    const float* __restrict__ den, float* __restrict__ outp)
{
  const int hh = blockIdx.x & 3;
  const int it = blockIdx.x >> 2;
  const int f = threadIdx.x & 31;
  const int ig = threadIdx.x >> 5;
  const int i = it * 16 + ig * 2;

  const float* prow = p + (size_t)hh * N_NODES * N_NODES + i;
  const float* gcol = gr + hh * N_HID + f;
  float n0 = 0.f, n1 = 0.f;
#pragma unroll 4
  for (int j = 0; j < N_NODES; ++j) {
    const float2 pv = *(const float2*)(prow + (size_t)j * N_NODES);
    const float gv = gcol[(size_t)j * OUT_F];
    n0 = fmaf(pv.x, gv, n0);
    n1 = fmaf(pv.y, gv, n1);
  }
  const float inv0 = 1.0f / den[hh * N_NODES + i + 0];
  const float inv1 = 1.0f / den[hh * N_NODES + i + 1];
  float v0 = n0 * inv0, v1 = n1 * inv1;
  v0 = v0 > 0.f ? v0 : expm1f(v0);
  v1 = v1 > 0.f ? v1 : expm1f(v1);
  outp[(size_t)(i + 0) * OUT_F + hh * N_HID + f] = v0;
  outp[(size_t)(i + 1) * OUT_F + hh * N_HID + f] = v1;
}

extern "C" void kernel_launch(void* const* d_in, const int* in_sizes, int n_in,
                              void* d_out, int out_size, void* d_ws, size_t ws_size,
                              hipStream_t stream) {
  const float* hmat  = (const float*)d_in[0];
  const int*   adj   = (const int*)d_in[1];
  const float* Wl    = (const float*)d_in[2];
  const float* Wr    = (const float*)d_in[3];
  const float* attnw = (const float*)d_in[4];
  float* outp = (float*)d_out;

  char* ws = (char*)d_ws;
  float* gl  = (float*)ws;                            // 512 KB
  float* gr  = (float*)(ws + 512 * 1024);             // 512 KB
  float* den = (float*)(ws + 1024 * 1024);            // 4*1024 f32 = 16 KB
  float* p   = (float*)(ws + 1024 * 1024 + 64 * 1024);// 16 MB

  gat_gemm<<<256, 256, 0, stream>>>(hmat, Wl, Wr, gl, gr, den);
  gat_escore<<<dim3(128, 32), 256, 0, stream>>>(gl, gr, attnw, adj, p, den);
  gat_aggr<<<256, 256, 0, stream>>>(p, gr, den, outp);
}

// Round 3
// 151.486 us; speedup vs baseline: 1.4504x; 1.4504x over previous
//
#include <hip/hip_runtime.h>
#include <math.h>

#define N_NODES 1024
#define IN_F 512
#define N_HEADS 4
#define N_HID 32
#define OUT_F 128   // N_HEADS*N_HID
#define GF 256      // fused g row: [0..127]=g_l, [128..255]=g_r
#define NEG_SLOPE 0.2f

// ---------------- Kernel 1: partial GEMM  gpart[kc][row][c] ----------------
// grid 512 = (it 64 x ct 4 x kc 2), 256 thr = (c4 16, r 16).
// Thread: 1 row x 4 fused cols, k-chunk 256, unroll 16 (16 b128 in flight).
// Blocks 0..15 also zero den[4][1024].
__global__ __launch_bounds__(256) void gat_gemm(
    const float* __restrict__ hmat, const float* __restrict__ Wl,
    const float* __restrict__ Wr, float* __restrict__ gpart,
    float* __restrict__ den)
{
  const int b = blockIdx.x;
  if (b < 16) den[b * 256 + threadIdx.x] = 0.f;
  const int kc = b & 1, ct = (b >> 1) & 3, it = b >> 3;
  const int c4 = threadIdx.x & 15, r = threadIdx.x >> 4;
  const int row = it * 16 + r;
  const int cb = ct * 64 + c4 * 4;  // fused col
  const float* __restrict__ W = (cb < 128) ? (Wl + cb) : (Wr + (cb - 128));
  const float* __restrict__ wp = W + (size_t)(kc * 256) * OUT_F;
  const float* __restrict__ hrow = hmat + (size_t)row * IN_F + kc * 256;

  float4 acc = make_float4(0.f, 0.f, 0.f, 0.f);
#pragma unroll 1
  for (int k = 0; k < 256; k += 16) {
    float4 w[16];
#pragma unroll
    for (int kk = 0; kk < 16; ++kk)
      w[kk] = *(const float4*)(wp + (size_t)(k + kk) * OUT_F);
    const float4 ha = *(const float4*)(hrow + k);
    const float4 hb = *(const float4*)(hrow + k + 4);
    const float4 hc = *(const float4*)(hrow + k + 8);
    const float4 hd = *(const float4*)(hrow + k + 12);
#define FM(s, kk)                                                            \
  acc.x = fmaf(s, w[kk].x, acc.x); acc.y = fmaf(s, w[kk].y, acc.y);          \
  acc.z = fmaf(s, w[kk].z, acc.z); acc.w = fmaf(s, w[kk].w, acc.w);
    FM(ha.x, 0) FM(ha.y, 1) FM(ha.z, 2) FM(ha.w, 3)
    FM(hb.x, 4) FM(hb.y, 5) FM(hb.z, 6) FM(hb.w, 7)
    FM(hc.x, 8) FM(hc.y, 9) FM(hc.z, 10) FM(hc.w, 11)
    FM(hd.x, 12) FM(hd.y, 13) FM(hd.z, 14) FM(hd.w, 15)
#undef FM
  }
  *(float4*)(gpart + ((size_t)kc * N_NODES + row) * GF + cb) = acc;
}

// ---------------- Kernel 2: g = gpart[0] + gpart[1] ------------------------
__global__ __launch_bounds__(256) void gat_reduceW(
    const float* __restrict__ gpart, float* __restrict__ g)
{
  const int idx = blockIdx.x * 256 + threadIdx.x;  // float4 index, 65536 total
  const float4 a = ((const float4*)gpart)[idx];
  const float4 b = ((const float4*)gpart)[idx + 65536];
  float4 o;
  o.x = a.x + b.x; o.y = a.y + b.y; o.z = a.z + b.z; o.w = a.w + b.w;
  ((float4*)g)[idx] = o;
}

// ---------------- Kernel 3: p^T[h][j][i] = adj ? exp(e) : 0; den atomics ---
// grid (128 it x 32 jt), 256 thr = (jl 32, hh 4, is 2); 4 i's per thread,
// g_r rows in registers, g_l j-tile in LDS. No max-subtraction (|e| <~ 3).
__global__ __launch_bounds__(256) void gat_escore(
    const float* __restrict__ g, const float* __restrict__ attn_w,
    const int* __restrict__ adj, float* __restrict__ p, float* __restrict__ den)
{
  __shared__ float4 gls[32][33];
  const int i0 = blockIdx.x * 8;
  const int jb = blockIdx.y * 32;
  {
    const int row = threadIdx.x >> 3;
    const int f4b = threadIdx.x & 7;
#pragma unroll
    for (int q = 0; q < 4; ++q) {
      const int f4 = f4b + 8 * q;
      gls[row][f4] = *(const float4*)(g + (size_t)(jb + row) * GF + f4 * 4);
    }
  }
  const int jl = threadIdx.x & 31;
  const int hh = (threadIdx.x >> 5) & 3;
  const int is = threadIdx.x >> 7;
  const int ibase = i0 + is * 4;

  float4 gg[4][8];
#pragma unroll
  for (int ii = 0; ii < 4; ++ii)
#pragma unroll
    for (int f4 = 0; f4 < 8; ++f4)
      gg[ii][f4] = *(const float4*)(g + (size_t)(ibase + ii) * GF + 128 +
                                    hh * N_HID + f4 * 4);
  float aw[N_HID];
#pragma unroll
  for (int f = 0; f < N_HID; ++f) aw[f] = attn_w[f];
  __syncthreads();

  float acc[4] = {0.f, 0.f, 0.f, 0.f};
#pragma unroll
  for (int f4 = 0; f4 < 8; ++f4) {
    const float4 gv = gls[jl][hh * 8 + f4];
#pragma unroll
    for (int ii = 0; ii < 4; ++ii) {
      float s;
      s = gv.x + gg[ii][f4].x;
      acc[ii] = fmaf(fmaxf(s, NEG_SLOPE * s), aw[f4 * 4 + 0], acc[ii]);
      s = gv.y + gg[ii][f4].y;
      acc[ii] = fmaf(fmaxf(s, NEG_SLOPE * s), aw[f4 * 4 + 1], acc[ii]);
      s = gv.z + gg[ii][f4].z;
      acc[ii] = fmaf(fmaxf(s, NEG_SLOPE * s), aw[f4 * 4 + 2], acc[ii]);
      s = gv.w + gg[ii][f4].w;
      acc[ii] = fmaf(fmaxf(s, NEG_SLOPE * s), aw[f4 * 4 + 3], acc[ii]);
    }
  }

  const int j = jb + jl;
  float4 pv;
  float* pvp = &pv.x;
#pragma unroll
  for (int ii = 0; ii < 4; ++ii) {
    const int a = adj[(size_t)(ibase + ii) * N_NODES + j];
    pvp[ii] = a ? __expf(acc[ii]) : 0.f;
  }
  *(float4*)(p + ((size_t)hh * N_NODES + j) * N_NODES + ibase) = pv;

  float d0 = pv.x, d1 = pv.y, d2 = pv.z, d3 = pv.w;
#pragma unroll
  for (int m = 1; m < 32; m <<= 1) {
    d0 += __shfl_xor(d0, m);
    d1 += __shfl_xor(d1, m);
    d2 += __shfl_xor(d2, m);
    d3 += __shfl_xor(d3, m);
  }
  if (jl == 0) {
    atomicAdd(&den[hh * N_NODES + ibase + 0], d0);
    atomicAdd(&den[hh * N_NODES + ibase + 1], d1);
    atomicAdd(&den[hh * N_NODES + ibase + 2], d2);
    atomicAdd(&den[hh * N_NODES + ibase + 3], d3);
  }
}

// ---------------- Kernel 4: hpart[jc][i][hf] = sum_{j in chunk} p*gr -------
// grid 512 = (jc 16, hh 4, it 8), 256 thr = (f2 16, ig 16).
// Thread: 2 f x 8 i register tile; p read along i (1 line/wave/j, broadcast).
__global__ __launch_bounds__(256) void gat_aggr(
    const float* __restrict__ p, const float* __restrict__ g,
    float* __restrict__ hpart)
{
  const int b = blockIdx.x;
  const int jc = b & 15, hh = (b >> 4) & 3, it = b >> 6;
  const int f2 = threadIdx.x & 15, ig = threadIdx.x >> 4;
  const int i = it * 128 + ig * 8;
  const int f = hh * N_HID + f2 * 2;
  const int j0 = jc * 64;

  const float* __restrict__ prow = p + (size_t)hh * N_NODES * N_NODES + i;
  const float* __restrict__ gcol = g + 128 + f;

  float a0 = 0.f, a1 = 0.f, a2 = 0.f, a3 = 0.f, a4 = 0.f, a5 = 0.f, a6 = 0.f,
        a7 = 0.f, a8 = 0.f, a9 = 0.f, a10 = 0.f, a11 = 0.f, a12 = 0.f,
        a13 = 0.f, a14 = 0.f, a15 = 0.f;
#pragma unroll 2
  for (int j = j0; j < j0 + 64; ++j) {
    const float4 p0 = *(const float4*)(prow + (size_t)j * N_NODES);
    const float4 p1 = *(const float4*)(prow + (size_t)j * N_NODES + 4);
    const float2 gv = *(const float2*)(gcol + (size_t)j * GF);
    a0  = fmaf(p0.x, gv.x, a0);  a1  = fmaf(p0.x, gv.y, a1);
    a2  = fmaf(p0.y, gv.x, a2);  a3  = fmaf(p0.y, gv.y, a3);
    a4  = fmaf(p0.z, gv.x, a4);  a5  = fmaf(p0.z, gv.y, a5);
    a6  = fmaf(p0.w, gv.x, a6);  a7  = fmaf(p0.w, gv.y, a7);
    a8  = fmaf(p1.x, gv.x, a8);  a9  = fmaf(p1.x, gv.y, a9);
    a10 = fmaf(p1.y, gv.x, a10); a11 = fmaf(p1.y, gv.y, a11);
    a12 = fmaf(p1.z, gv.x, a12); a13 = fmaf(p1.z, gv.y, a13);
    a14 = fmaf(p1.w, gv.x, a14); a15 = fmaf(p1.w, gv.y, a15);
  }
  float* hp = hpart + ((size_t)jc * N_NODES + i) * OUT_F + f;
  *(float2*)(hp + 0 * OUT_F) = make_float2(a0, a1);
  *(float2*)(hp + 1 * OUT_F) = make_float2(a2, a3);
  *(float2*)(hp + 2 * OUT_F) = make_float2(a4, a5);
  *(float2*)(hp + 3 * OUT_F) = make_float2(a6, a7);
  *(float2*)(hp + 4 * OUT_F) = make_float2(a8, a9);
  *(float2*)(hp + 5 * OUT_F) = make_float2(a10, a11);
  *(float2*)(hp + 6 * OUT_F) = make_float2(a12, a13);
  *(float2*)(hp + 7 * OUT_F) = make_float2(a14, a15);
}

// ---------------- Kernel 5: out = ELU( sum_c hpart[c] / den ) --------------
__global__ __launch_bounds__(256) void gat_fin(
    const float* __restrict__ hpart, const float* __restrict__ den,
    float* __restrict__ outp)
{
  const int flat = blockIdx.x * 256 + threadIdx.x;  // i*128+hf
  const int i = flat >> 7, hf = flat & 127, hh = hf >> 5;
  float t[16];
#pragma unroll
  for (int c = 0; c < 16; ++c) t[c] = hpart[(size_t)c * (N_NODES * OUT_F) + flat];
  float s0 = (t[0] + t[1]) + (t[2] + t[3]);
  float s1 = (t[4] + t[5]) + (t[6] + t[7]);
  float s2 = (t[8] + t[9]) + (t[10] + t[11]);
  float s3 = (t[12] + t[13]) + (t[14] + t[15]);
  float s = (s0 + s1) + (s2 + s3);
  float v = s / den[hh * N_NODES + i];
  outp[flat] = v > 0.f ? v : expm1f(v);
}

extern "C" void kernel_launch(void* const* d_in, const int* in_sizes, int n_in,
                              void* d_out, int out_size, void* d_ws, size_t ws_size,
                              hipStream_t stream) {
  const float* hmat  = (const float*)d_in[0];
  const int*   adj   = (const int*)d_in[1];
  const float* Wl    = (const float*)d_in[2];
  const float* Wr    = (const float*)d_in[3];
  const float* attnw = (const float*)d_in[4];
  float* outp = (float*)d_out;

  char* ws = (char*)d_ws;
  float* gpart = (float*)(ws);                        // 2 x 1024 x 256 = 2 MB
  float* g     = (float*)(ws + (2u << 20));           // 1024 x 256 = 1 MB
  float* den   = (float*)(ws + (3u << 20));           // 4 x 1024 = 16 KB
  float* p     = (float*)(ws + (4u << 20));           // 4 x 1024 x 1024 = 16 MB
  float* hpart = (float*)(ws + (20u << 20));          // 16 x 1024 x 128 = 8 MB

  gat_gemm<<<512, 256, 0, stream>>>(hmat, Wl, Wr, gpart, den);
  gat_reduceW<<<256, 256, 0, stream>>>(gpart, g);
  gat_escore<<<dim3(128, 32), 256, 0, stream>>>(g, attnw, adj, p, den);
  gat_aggr<<<512, 256, 0, stream>>>(p, g, hpart);
  gat_fin<<<512, 256, 0, stream>>>(hpart, den, outp);
}

// Round 4
// 115.493 us; speedup vs baseline: 1.9024x; 1.3116x over previous
//
#include <hip/hip_runtime.h>
#include <math.h>

#define N_NODES 1024
#define IN_F 512
#define N_HEADS 4
#define N_HID 32
#define OUT_F 128   // N_HEADS*N_HID
#define GF 256      // fused g row: [0..127]=g_l, [128..255]=g_r
#define NEG_SLOPE 0.2f

// ---------------- Kernel 1: LDS-tiled partial GEMM gpart[kc][row][c] -------
// grid 512 = (it 16 x ct 4 x kc 8), 256 thr. BM=BN=64, k-chunk 64, TK=16.
// Thread tile 4x4. A staged TRANSPOSED As[k][row] (pad 68: b128 reads 2-way,
// b32 transpose-writes conflict-free). Next-chunk regs prefetched during FMAs.
__global__ __launch_bounds__(256, 2) void gat_gemm(
    const float* __restrict__ hmat, const float* __restrict__ Wl,
    const float* __restrict__ Wr, float* __restrict__ gpart,
    float* __restrict__ den)
{
  const int b = blockIdx.x;
  if (b < 16) den[b * 256 + threadIdx.x] = 0.f;
  const int kc = b & 7, ct = (b >> 3) & 3, it = b >> 5;
  const int i0 = it * 64, k0 = kc * 64, cb0 = ct * 64;
  const float* __restrict__ W = (cb0 < 128) ? (Wl + cb0) : (Wr + (cb0 - 128));

  __shared__ float As[16][68];  // [k][row], 68-pad: 272B row = 17x16B aligned
  __shared__ float Bs[16][64];  // [k][col]

  const int tx = threadIdx.x & 15, ty = threadIdx.x >> 4;
  const int ar = threadIdx.x >> 2, ak = (threadIdx.x & 3) * 4;  // A stage
  const int bk = threadIdx.x >> 4, bc = (threadIdx.x & 15) * 4; // B stage

  float4 acc0 = {0.f, 0.f, 0.f, 0.f}, acc1 = acc0, acc2 = acc0, acc3 = acc0;

  float4 av = *(const float4*)(hmat + (size_t)(i0 + ar) * IN_F + k0 + ak);
  float4 bv = *(const float4*)(W + (size_t)(k0 + bk) * OUT_F + bc);

  for (int t = 0; t < 64; t += 16) {
    __syncthreads();
    As[ak + 0][ar] = av.x; As[ak + 1][ar] = av.y;
    As[ak + 2][ar] = av.z; As[ak + 3][ar] = av.w;
    *(float4*)&Bs[bk][bc] = bv;
    __syncthreads();
    if (t < 48) {  // prefetch next chunk while computing this one
      av = *(const float4*)(hmat + (size_t)(i0 + ar) * IN_F + k0 + t + 16 + ak);
      bv = *(const float4*)(W + (size_t)(k0 + t + 16 + bk) * OUT_F + bc);
    }
#pragma unroll
    for (int k = 0; k < 16; ++k) {
      const float4 a  = *(const float4*)&As[k][ty * 4];
      const float4 bb = *(const float4*)&Bs[k][tx * 4];
      acc0.x = fmaf(a.x, bb.x, acc0.x); acc0.y = fmaf(a.x, bb.y, acc0.y);
      acc0.z = fmaf(a.x, bb.z, acc0.z); acc0.w = fmaf(a.x, bb.w, acc0.w);
      acc1.x = fmaf(a.y, bb.x, acc1.x); acc1.y = fmaf(a.y, bb.y, acc1.y);
      acc1.z = fmaf(a.y, bb.z, acc1.z); acc1.w = fmaf(a.y, bb.w, acc1.w);
      acc2.x = fmaf(a.z, bb.x, acc2.x); acc2.y = fmaf(a.z, bb.y, acc2.y);
      acc2.z = fmaf(a.z, bb.z, acc2.z); acc2.w = fmaf(a.z, bb.w, acc2.w);
      acc3.x = fmaf(a.w, bb.x, acc3.x); acc3.y = fmaf(a.w, bb.y, acc3.y);
      acc3.z = fmaf(a.w, bb.z, acc3.z); acc3.w = fmaf(a.w, bb.w, acc3.w);
    }
  }
  const size_t rbase = (size_t)kc * N_NODES + i0 + ty * 4;
  const int cc = cb0 + tx * 4;
  *(float4*)(gpart + (rbase + 0) * GF + cc) = acc0;
  *(float4*)(gpart + (rbase + 1) * GF + cc) = acc1;
  *(float4*)(gpart + (rbase + 2) * GF + cc) = acc2;
  *(float4*)(gpart + (rbase + 3) * GF + cc) = acc3;
}

// ---------------- Kernel 2: g = sum of 8 k-partials ------------------------
__global__ __launch_bounds__(256) void gat_reduceW(
    const float4* __restrict__ gp, float4* __restrict__ g)
{
  const int idx = blockIdx.x * 256 + threadIdx.x;  // 65536 float4
  float4 s = gp[idx];
#pragma unroll
  for (int c = 1; c < 8; ++c) {
    const float4 v = gp[idx + c * 65536];
    s.x += v.x; s.y += v.y; s.z += v.z; s.w += v.w;
  }
  g[idx] = s;
}

// ---------------- Kernel 3: p^T[h][j][i] = adj ? exp(e) : 0; den atomics ---
// grid (128 it x 32 jt), 256 thr = (jl 32, hh 4, is 2); 4 i's per thread,
// g_r rows in registers, g_l j-tile in LDS. No max-subtraction (|e| <~ 3).
__global__ __launch_bounds__(256) void gat_escore(
    const float* __restrict__ g, const float* __restrict__ attn_w,
    const int* __restrict__ adj, float* __restrict__ p, float* __restrict__ den)
{
  __shared__ float4 gls[32][33];
  const int i0 = blockIdx.x * 8;
  const int jb = blockIdx.y * 32;
  {
    const int row = threadIdx.x >> 3;
    const int f4b = threadIdx.x & 7;
#pragma unroll
    for (int q = 0; q < 4; ++q) {
      const int f4 = f4b + 8 * q;
      gls[row][f4] = *(const float4*)(g + (size_t)(jb + row) * GF + f4 * 4);
    }
  }
  const int jl = threadIdx.x & 31;
  const int hh = (threadIdx.x >> 5) & 3;
  const int is = threadIdx.x >> 7;
  const int ibase = i0 + is * 4;

  float4 gg[4][8];
#pragma unroll
  for (int ii = 0; ii < 4; ++ii)
#pragma unroll
    for (int f4 = 0; f4 < 8; ++f4)
      gg[ii][f4] = *(const float4*)(g + (size_t)(ibase + ii) * GF + 128 +
                                    hh * N_HID + f4 * 4);
  float aw[N_HID];
#pragma unroll
  for (int f = 0; f < N_HID; ++f) aw[f] = attn_w[f];
  __syncthreads();

  float acc[4] = {0.f, 0.f, 0.f, 0.f};
#pragma unroll
  for (int f4 = 0; f4 < 8; ++f4) {
    const float4 gv = gls[jl][hh * 8 + f4];
#pragma unroll
    for (int ii = 0; ii < 4; ++ii) {
      float s;
      s = gv.x + gg[ii][f4].x;
      acc[ii] = fmaf(fmaxf(s, NEG_SLOPE * s), aw[f4 * 4 + 0], acc[ii]);
      s = gv.y + gg[ii][f4].y;
      acc[ii] = fmaf(fmaxf(s, NEG_SLOPE * s), aw[f4 * 4 + 1], acc[ii]);
      s = gv.z + gg[ii][f4].z;
      acc[ii] = fmaf(fmaxf(s, NEG_SLOPE * s), aw[f4 * 4 + 2], acc[ii]);
      s = gv.w + gg[ii][f4].w;
      acc[ii] = fmaf(fmaxf(s, NEG_SLOPE * s), aw[f4 * 4 + 3], acc[ii]);
    }
  }

  const int j = jb + jl;
  float4 pv;
  float* pvp = &pv.x;
#pragma unroll
  for (int ii = 0; ii < 4; ++ii) {
    const int a = adj[(size_t)(ibase + ii) * N_NODES + j];
    pvp[ii] = a ? __expf(acc[ii]) : 0.f;
  }
  *(float4*)(p + ((size_t)hh * N_NODES + j) * N_NODES + ibase) = pv;

  float d0 = pv.x, d1 = pv.y, d2 = pv.z, d3 = pv.w;
#pragma unroll
  for (int m = 1; m < 32; m <<= 1) {
    d0 += __shfl_xor(d0, m);
    d1 += __shfl_xor(d1, m);
    d2 += __shfl_xor(d2, m);
    d3 += __shfl_xor(d3, m);
  }
  if (jl == 0) {
    atomicAdd(&den[hh * N_NODES + ibase + 0], d0);
    atomicAdd(&den[hh * N_NODES + ibase + 1], d1);
    atomicAdd(&den[hh * N_NODES + ibase + 2], d2);
    atomicAdd(&den[hh * N_NODES + ibase + 3], d3);
  }
}

// ---------------- Kernel 4: LDS-tiled aggregation partials -----------------
// hpart[jc][i][hf] = sum_{j in 128-chunk} p^T[h][j][i] * gr[j][hf].
// grid 512 = (jc 8 x hh 4 x it 16), 256 thr = (f2 16, ig 16).
// Stage Ps[16 j][64 i] (p read exactly once, coalesced) + Gs[16 j][32 f];
// thread tile 4 i x 2 f; next chunk reg-prefetched during FMAs.
__global__ __launch_bounds__(256, 2) void gat_aggr(
    const float* __restrict__ p, const float* __restrict__ g,
    float* __restrict__ hpart)
{
  const int b = blockIdx.x;
  const int jc = b & 7, hh = (b >> 3) & 3, it = b >> 5;
  const int i0 = it * 64, j0 = jc * 128;

  __shared__ float Ps[16][64];
  __shared__ float Gs[16][32];

  const int f2 = threadIdx.x & 15, ig = threadIdx.x >> 4;
  const int pj = threadIdx.x >> 4, pi = (threadIdx.x & 15) * 4;
  const int gj = threadIdx.x >> 3, gf = (threadIdx.x & 7) * 4;

  const float* __restrict__ pbase =
      p + (size_t)hh * N_NODES * N_NODES + i0 + pi;
  const float* __restrict__ gbase = g + 128 + hh * N_HID + gf;

  float a00 = 0.f, a01 = 0.f, a10 = 0.f, a11 = 0.f;
  float a20 = 0.f, a21 = 0.f, a30 = 0.f, a31 = 0.f;

  float4 pv = *(const float4*)(pbase + (size_t)(j0 + pj) * N_NODES);
  float4 gv = {0.f, 0.f, 0.f, 0.f};
  if (threadIdx.x < 128)
    gv = *(const float4*)(gbase + (size_t)(j0 + gj) * GF);

  for (int c = 0; c < 8; ++c) {
    __syncthreads();
    *(float4*)&Ps[pj][pi] = pv;
    if (threadIdx.x < 128) *(float4*)&Gs[gj][gf] = gv;
    __syncthreads();
    if (c < 7) {
      pv = *(const float4*)(pbase + (size_t)(j0 + (c + 1) * 16 + pj) * N_NODES);
      if (threadIdx.x < 128)
        gv = *(const float4*)(gbase + (size_t)(j0 + (c + 1) * 16 + gj) * GF);
    }
#pragma unroll
    for (int k = 0; k < 16; ++k) {
      const float4 pp = *(const float4*)&Ps[k][ig * 4];
      const float2 gg = *(const float2*)&Gs[k][f2 * 2];
      a00 = fmaf(pp.x, gg.x, a00); a01 = fmaf(pp.x, gg.y, a01);
      a10 = fmaf(pp.y, gg.x, a10); a11 = fmaf(pp.y, gg.y, a11);
      a20 = fmaf(pp.z, gg.x, a20); a21 = fmaf(pp.z, gg.y, a21);
      a30 = fmaf(pp.w, gg.x, a30); a31 = fmaf(pp.w, gg.y, a31);
    }
  }
  float* hp = hpart + ((size_t)jc * N_NODES + i0 + ig * 4) * OUT_F +
              hh * N_HID + f2 * 2;
  *(float2*)(hp + 0 * OUT_F) = make_float2(a00, a01);
  *(float2*)(hp + 1 * OUT_F) = make_float2(a10, a11);
  *(float2*)(hp + 2 * OUT_F) = make_float2(a20, a21);
  *(float2*)(hp + 3 * OUT_F) = make_float2(a30, a31);
}

// ---------------- Kernel 5: out = ELU( sum_c hpart[c] / den ) --------------
__global__ __launch_bounds__(256) void gat_fin(
    const float* __restrict__ hpart, const float* __restrict__ den,
    float* __restrict__ outp)
{
  const int flat = blockIdx.x * 256 + threadIdx.x;  // i*128+hf
  const int i = flat >> 7, hf = flat & 127, hh = hf >> 5;
  float t[8];
#pragma unroll
  for (int c = 0; c < 8; ++c)
    t[c] = hpart[(size_t)c * (N_NODES * OUT_F) + flat];
  float s = ((t[0] + t[1]) + (t[2] + t[3])) + ((t[4] + t[5]) + (t[6] + t[7]));
  float v = s / den[hh * N_NODES + i];
  outp[flat] = v > 0.f ? v : expm1f(v);
}

extern "C" void kernel_launch(void* const* d_in, const int* in_sizes, int n_in,
                              void* d_out, int out_size, void* d_ws, size_t ws_size,
                              hipStream_t stream) {
  const float* hmat  = (const float*)d_in[0];
  const int*   adj   = (const int*)d_in[1];
  const float* Wl    = (const float*)d_in[2];
  const float* Wr    = (const float*)d_in[3];
  const float* attnw = (const float*)d_in[4];
  float* outp = (float*)d_out;

  char* ws = (char*)d_ws;
  float* gpart = (float*)(ws);                 // 8 x 1024 x 256 f32 = 8 MB
  float* g     = (float*)(ws + (8u << 20));    // 1024 x 256 f32 = 1 MB
  float* den   = (float*)(ws + (9u << 20));    // 4 x 1024 f32 = 16 KB
  float* p     = (float*)(ws + (10u << 20));   // 4 x 1024 x 1024 f32 = 16 MB
  float* hpart = (float*)(ws + (26u << 20));   // 8 x 1024 x 128 f32 = 4 MB

  gat_gemm<<<512, 256, 0, stream>>>(hmat, Wl, Wr, gpart, den);
  gat_reduceW<<<256, 256, 0, stream>>>((const float4*)gpart, (float4*)g);
  gat_escore<<<dim3(128, 32), 256, 0, stream>>>(g, attnw, adj, p, den);
  gat_aggr<<<512, 256, 0, stream>>>(p, g, hpart);
  gat_fin<<<512, 256, 0, stream>>>(hpart, den, outp);
}